// Round 14
// baseline (200.095 us; speedup 1.0000x reference)
//
#include <hip/hip_runtime.h>

#define H_IN 448
#define W_IN 448
#define HW_IN (H_IN * W_IN)
#define BGW 488
#define BGHW (BGW * BGW)
#define OUTI 256
#define OUTI_PIX (OUTI * OUTI)
#define OUTM 64
#define B_SAMPLES 64
#define BBOX_CHUNKS 16
#define BBOX_ROWS (H_IN / BBOX_CHUNKS)  // 28
#define BITS_STRIDE 8                    // u64 words per row
#define RPB 4                            // output rows per block
#define NGRP (OUTI / RPB)                // 64 row-groups
#define SPAN 10                          // max source-row span for 4 output rows (<= 9.6+1)

typedef unsigned long long u64;

__device__ __forceinline__ float clamp01(float x) { return fminf(fmaxf(x, 0.f), 1.f); }
__device__ __forceinline__ int clampi(int x, int lo, int hi) { return min(max(x, lo), hi); }

// ---------------- K1: bbox + packed mask bitmask (round-13 verbatim) ----------------
__global__ void k_bbox(const float* __restrict__ ms, int* __restrict__ bbox,
                       u64* __restrict__ bits) {
    int b = blockIdx.y, chunk = blockIdx.x;
    int tid = threadIdx.x;
    int wave = tid >> 6, lane = tid & 63;
    const float* msB = ms + (size_t)b * HW_IN;
    u64* bitsB = bits + (size_t)b * H_IN * BITS_STRIDE;

    int miny = H_IN, maxy = -1, minx = W_IN, maxx = -1;
    for (int rr = wave; rr < BBOX_ROWS; rr += 4) {
        int row = chunk * BBOX_ROWS + rr;
        const float4* rowp = (const float4*)(msB + (size_t)row * W_IN);
#pragma unroll
        for (int sub = 0; sub < 2; ++sub) {
            int c4 = sub * 64 + lane;
            bool valid = c4 < (W_IN / 4);
            float4 v = rowp[min(c4, W_IN / 4 - 1)];
            bool a0 = valid && (v.x > 0.5f);
            bool a1 = valid && (v.y > 0.5f);
            bool a2 = valid && (v.z > 0.5f);
            bool a3 = valid && (v.w > 0.5f);
            u64 b0 = __ballot(a0), b1 = __ballot(a1), b2 = __ballot(a2), b3 = __ballot(a3);
            if (a0 | a1 | a2 | a3) {
                miny = min(miny, row); maxy = max(maxy, row);
                int xb = c4 * 4;
                if (a0) { minx = min(minx, xb);     maxx = max(maxx, xb); }
                if (a1) { minx = min(minx, xb + 1); maxx = max(maxx, xb + 1); }
                if (a2) { minx = min(minx, xb + 2); maxx = max(maxx, xb + 2); }
                if (a3) { minx = min(minx, xb + 3); maxx = max(maxx, xb + 3); }
            }
            if (lane < 4) {
                u64 w = (lane == 0) ? b0 : (lane == 1) ? b1 : (lane == 2) ? b2 : b3;
                bitsB[(size_t)row * BITS_STRIDE + sub * 4 + lane] = w;
            }
        }
    }
    __shared__ int s[4];
    if (tid == 0) { s[0] = H_IN; s[1] = -1; s[2] = W_IN; s[3] = -1; }
    __syncthreads();
    atomicMin(&s[0], miny); atomicMax(&s[1], maxy);
    atomicMin(&s[2], minx); atomicMax(&s[3], maxx);
    __syncthreads();
    if (tid == 0) {
        atomicMin(&bbox[b * 4 + 0], s[0]);
        atomicMin(&bbox[b * 4 + 1], -s[1]);
        atomicMin(&bbox[b * 4 + 2], s[2]);
        atomicMin(&bbox[b * 4 + 3], -s[3]);
    }
}

struct Geo {
    int miny, minx, h, w, top, left, Hp, Wp;
};
__device__ __forceinline__ Geo load_geo(const int* __restrict__ bbox,
                                        const int* __restrict__ pads, int b) {
    Geo g;
    g.miny = bbox[b * 4 + 0];
    int maxy = -bbox[b * 4 + 1];
    g.minx = bbox[b * 4 + 2];
    int maxx = -bbox[b * 4 + 3];
    int left = pads[b * 4 + 0], right = pads[b * 4 + 1];
    int top = pads[b * 4 + 2], bot = pads[b * 4 + 3];
    g.h = maxy - g.miny + 1;
    g.w = maxx - g.minx + 1;
    g.top = top; g.left = left;
    g.Hp = g.h + top + bot;
    g.Wp = g.w + left + right;
    return g;
}

__device__ __forceinline__ void src_coord(int i, int n_out, int size,
                                          int& t0, int& t1, float& frac) {
    float sizef = (float)size;
    float t = (i + 0.5f) * (sizef / (float)n_out) - 0.5f;
    t = fminf(fmaxf(t, 0.f), sizef - 1.f);
    t0 = (int)floorf(t);
    t1 = min(t0 + 1, size - 1);
    frac = t - (float)t0;
}

__device__ __forceinline__ bool mask_bit(const u64* rowbits, int c) {
    u64 w = rowbits[((c >> 8) << 2) | (c & 3)];
    return (w >> ((c >> 2) & 63)) & 1ULL;
}

struct RowGeom {
    int y0, y1, r0, r1;
    float wy;
    bool incy0, incy1;
};
__device__ __forceinline__ RowGeom row_geom(const Geo& g, int oy) {
    RowGeom rg;
    src_coord(oy, OUTI, g.Hp, rg.y0, rg.y1, rg.wy);
    rg.r0 = clampi(g.miny + rg.y0 - g.top, 0, H_IN - 1);
    rg.r1 = clampi(g.miny + rg.y1 - g.top, 0, H_IN - 1);
    rg.incy0 = (rg.y0 >= g.top) && (rg.y0 < g.top + g.h);
    rg.incy1 = (rg.y1 >= g.top) && (rg.y1 < g.top + g.h);
    return rg;
}

__device__ __forceinline__ unsigned short q16(float x) {
    return (unsigned short)__float2uint_rn(x * 65535.f);
}

// ---------------- K2: long-stream multi-row resize (u16 LDS) ----------------
// Block = 4 output rows of one sample. Stages the contiguous <=10-source-row span of
// img (3ch) and bg (3ch) as LONG coalesced streams (~18 KB/channel), converting f32->u16
// into LDS. Compute identical to round-13, reading u16.
__global__ void __launch_bounds__(256) k_resize_img(
        const float* __restrict__ img, const float* __restrict__ bg,
        const int* __restrict__ pads, const int* __restrict__ csel,
        const float* __restrict__ rcol, const float* __restrict__ jit,
        const int* __restrict__ bbox, const u64* __restrict__ bits,
        unsigned short* __restrict__ mid, float* __restrict__ partials) {
    int grp = blockIdx.x;     // row-group 0..63
    int b = blockIdx.y;       // sample
    int tid = threadIdx.x;    // output col

    Geo g = load_geo(bbox, pads, b);
    bool useBg = csel[b] > 2;
    float c0 = rcol[b * 3 + 0], c1 = rcol[b * 3 + 1], c2 = rcol[b * 3 + 2];
    float bfac = 0.9f + 0.2f * jit[b * 4 + 0];

    RowGeom rg[RPB];
#pragma unroll
    for (int t = 0; t < RPB; ++t) rg[t] = row_geom(g, grp * RPB + t);
    int R0 = rg[0].r0, R1 = rg[RPB - 1].r1;       // img row span (monotone)
    int Y0 = rg[0].y0, Y1 = rg[RPB - 1].y1;       // bg row span
    int NRi = R1 - R0 + 1;                        // <= SPAN
    int NRb = Y1 - Y0 + 1;                        // <= SPAN

    __shared__ unsigned short s_im[3][SPAN][W_IN];   // 26.9 KB
    __shared__ unsigned short s_bg[3][SPAN][BGW];    // 29.3 KB
    __shared__ u64 s_bits[SPAN][BITS_STRIDE];        // 640 B
    __shared__ float ls[4];

    const float* imB = img + (size_t)b * 3 * HW_IN;
    const u64* bitsB = bits + (size_t)b * H_IN * BITS_STRIDE;

    // img staging: per channel, one contiguous NRi*448-float stream, f32 -> u16
#pragma unroll
    for (int ch = 0; ch < 3; ++ch) {
        const float4* src = (const float4*)(imB + (size_t)ch * HW_IN + (size_t)R0 * W_IN);
        int n4 = NRi * (W_IN / 4);
        for (int i = tid; i < n4; i += 256) {
            int row = i / (W_IN / 4);
            int idx = i - row * (W_IN / 4);
            float4 v = src[i];
            ushort4 u = {q16(v.x), q16(v.y), q16(v.z), q16(v.w)};
            *(ushort4*)&s_im[ch][row][idx * 4] = u;
        }
    }
    if (useBg) {
        const float* bgB = bg + (size_t)b * 3 * BGHW;
#pragma unroll
        for (int ch = 0; ch < 3; ++ch) {
            const float4* src = (const float4*)(bgB + (size_t)ch * BGHW + (size_t)Y0 * BGW);
            int n4 = NRb * (BGW / 4);
            for (int i = tid; i < n4; i += 256) {
                int row = i / (BGW / 4);
                int idx = i - row * (BGW / 4);
                float4 v = src[i];
                ushort4 u = {q16(v.x), q16(v.y), q16(v.z), q16(v.w)};
                *(ushort4*)&s_bg[ch][row][idx * 4] = u;
            }
        }
    }
    if (tid < NRi * BITS_STRIDE) {
        int row = tid >> 3, idx = tid & 7;
        s_bits[row][idx] = bitsB[(size_t)(R0 + row) * BITS_STRIDE + idx];
    }
    __syncthreads();

    // column-side constants
    int x0, x1; float wx;
    src_coord(tid, OUTI, g.Wp, x0, x1, wx);
    int cA = clampi(g.minx + x0 - g.left, 0, W_IN - 1);
    int cB = clampi(g.minx + x1 - g.left, 0, W_IN - 1);
    bool inxA = (x0 >= g.left) && (x0 < g.left + g.w);
    bool inxB = (x1 >= g.left) && (x1 < g.left + g.w);

    const float S = 1.f / 65535.f;
    float gacc = 0.f;
#pragma unroll
    for (int t = 0; t < RPB; ++t) {
        float acc0 = 0.f, acc1 = 0.f, acc2 = 0.f;
#pragma unroll
        for (int tap = 0; tap < 4; ++tap) {
            int ky = tap >> 1;
            int Q = (tap & 1) ? x1 : x0;
            int c = (tap & 1) ? cB : cA;
            float wgt = (ky ? rg[t].wy : 1.f - rg[t].wy) * ((tap & 1) ? wx : 1.f - wx);
            bool incy = ky ? rg[t].incy1 : rg[t].incy0;
            bool in_crop = incy && ((tap & 1) ? inxB : inxA);
            int rr = (ky ? rg[t].r1 : rg[t].r0) - R0;
            bool mm = in_crop && mask_bit(s_bits[rr], c);
            float i0 = s_im[0][rr][c] * S;
            float i1 = s_im[1][rr][c] * S;
            float i2 = s_im[2][rr][c] * S;
            float b0, b1, b2;
            if (useBg) {   // block-uniform
                int br = (ky ? rg[t].y1 : rg[t].y0) - Y0;
                b0 = s_bg[0][br][Q] * S;
                b1 = s_bg[1][br][Q] * S;
                b2 = s_bg[2][br][Q] * S;
            } else {
                b0 = c0; b1 = c1; b2 = c2;
            }
            acc0 += wgt * (mm ? i0 : b0);
            acc1 += wgt * (mm ? i1 : b1);
            acc2 += wgt * (mm ? i2 : b2);
        }
        float o0 = clamp01(acc0 * bfac);
        float o1 = clamp01(acc1 * bfac);
        float o2 = clamp01(acc2 * bfac);
        size_t o = (size_t)b * 3 * OUTI_PIX + (size_t)(grp * RPB + t) * OUTI + tid;
        mid[o] = q16(o0);
        mid[o + OUTI_PIX] = q16(o1);
        mid[o + 2 * OUTI_PIX] = q16(o2);
        gacc += 0.299f * o0 + 0.587f * o1 + 0.114f * o2;
    }

    // deterministic per-group gray partial
#pragma unroll
    for (int off = 32; off > 0; off >>= 1) gacc += __shfl_down(gacc, off, 64);
    int wave = tid >> 6, lane = tid & 63;
    if (lane == 0) ls[wave] = gacc;
    __syncthreads();
    if (tid == 0)
        partials[b * NGRP + grp] = ls[0] + ls[1] + ls[2] + ls[3];
}

// ---------------- K2b: mask resize to 64x64 from the bitmask (round-13 verbatim) --------
__global__ void k_resize_msk(const u64* __restrict__ bits, const int* __restrict__ pads,
                             const int* __restrict__ bbox, float* __restrict__ outm) {
    int b = blockIdx.y;
    int pix = blockIdx.x * blockDim.x + threadIdx.x;
    int oy = pix >> 6, ox = pix & 63;

    Geo g = load_geo(bbox, pads, b);
    int y0, y1, x0, x1; float wy, wx;
    src_coord(oy, OUTM, g.Hp, y0, y1, wy);
    src_coord(ox, OUTM, g.Wp, x0, x1, wx);

    const u64* bitsB = bits + (size_t)b * H_IN * BITS_STRIDE;
    float acc = 0.f;
#pragma unroll
    for (int tap = 0; tap < 4; ++tap) {
        int P = (tap & 2) ? y1 : y0;
        int Q = (tap & 1) ? x1 : x0;
        float wgt = ((tap & 2) ? wy : 1.f - wy) * ((tap & 1) ? wx : 1.f - wx);
        bool in_crop = (P >= g.top) && (P < g.top + g.h) && (Q >= g.left) && (Q < g.left + g.w);
        int r = clampi(g.miny + P - g.top, 0, H_IN - 1);
        int c = clampi(g.minx + Q - g.left, 0, W_IN - 1);
        bool mm = in_crop && mask_bit(bitsB + (size_t)r * BITS_STRIDE, c);
        acc += wgt * (mm ? 1.f : 0.f);
    }
    outm[(size_t)b * (OUTM * OUTM) + pix] = acc;
}

// ---------------- K3: jitter, u16 intermediate -> f32 out (round-13, 64 partials) ------
__device__ __forceinline__ void jitter_px(float& r, float& g, float& bl,
                                          float cc, float ssf, float hd, float mean) {
    r = clamp01(cc * r + (1.f - cc) * mean);
    g = clamp01(cc * g + (1.f - cc) * mean);
    bl = clamp01(cc * bl + (1.f - cc) * mean);
    float gray = 0.299f * r + 0.587f * g + 0.114f * bl;
    r = clamp01(ssf * r + (1.f - ssf) * gray);
    g = clamp01(ssf * g + (1.f - ssf) * gray);
    bl = clamp01(ssf * bl + (1.f - ssf) * gray);
    float mx = fmaxf(r, fmaxf(g, bl));
    float mn = fminf(r, fminf(g, bl));
    float d = mx - mn;
    float dsv = (d > 0.f) ? d : 1.f;
    float hch;
    if (mx == r) {
        float t = (g - bl) / dsv;
        t = fmodf(t, 6.f);
        if (t < 0.f) t += 6.f;
        hch = t;
    } else if (mx == g) {
        hch = (bl - r) / dsv + 2.f;
    } else {
        hch = (r - g) / dsv + 4.f;
    }
    hch = (d > 0.f) ? hch * (1.f / 6.f) : 0.f;
    float sat = (mx > 0.f) ? d / mx : 0.f;
    float v = mx;
    float hh = hch + hd;
    hh -= floorf(hh);
    float h6 = hh * 6.f;
    float fi = floorf(h6);
    float f = h6 - fi;
    float pp = v * (1.f - sat);
    float q = v * (1.f - f * sat);
    float t = v * (1.f - (1.f - f) * sat);
    int im = ((int)fi) % 6;
    float ro, go, bo;
    switch (im) {
        case 0: ro = v;  go = t;  bo = pp; break;
        case 1: ro = q;  go = v;  bo = pp; break;
        case 2: ro = pp; go = v;  bo = t;  break;
        case 3: ro = pp; go = q;  bo = v;  break;
        case 4: ro = t;  go = pp; bo = v;  break;
        default: ro = v; go = pp; bo = q;  break;
    }
    r = clamp01(ro); g = clamp01(go); bl = clamp01(bo);
}

__global__ void k_jitter(const unsigned short* __restrict__ mid,
                         float* __restrict__ out, const float* __restrict__ jit,
                         const float* __restrict__ partials) {
    int b = blockIdx.y;
    int tid = threadIdx.x;

    float pv = (tid < NGRP) ? partials[b * NGRP + tid] : 0.f;
#pragma unroll
    for (int off = 32; off > 0; off >>= 1) pv += __shfl_down(pv, off, 64);
    __shared__ float ls[4];
    int wid = tid >> 6, lane = tid & 63;
    if (lane == 0) ls[wid] = pv;
    __syncthreads();
    float mean = (ls[0] + ls[1] + ls[2] + ls[3]) * (1.f / (float)OUTI_PIX);

    float cc = 0.9f + 0.2f * jit[b * 4 + 1];
    float ssf = 0.9f + 0.2f * jit[b * 4 + 2];
    float hd = -0.1f + 0.2f * jit[b * 4 + 3];

    int idx4 = blockIdx.x * blockDim.x + tid;
    const ushort4* mr = (const ushort4*)(mid + (size_t)b * 3 * OUTI_PIX) + idx4;
    const ushort4* mg = mr + OUTI_PIX / 4;
    const ushort4* mb = mr + 2 * (OUTI_PIX / 4);
    ushort4 ur = *mr, ug = *mg, ub = *mb;

    const float S = 1.f / 65535.f;
    float r0 = ur.x * S, r1 = ur.y * S, r2 = ur.z * S, r3 = ur.w * S;
    float g0 = ug.x * S, g1 = ug.y * S, g2 = ug.z * S, g3 = ug.w * S;
    float b0 = ub.x * S, b1 = ub.y * S, b2 = ub.z * S, b3 = ub.w * S;

    jitter_px(r0, g0, b0, cc, ssf, hd, mean);
    jitter_px(r1, g1, b1, cc, ssf, hd, mean);
    jitter_px(r2, g2, b2, cc, ssf, hd, mean);
    jitter_px(r3, g3, b3, cc, ssf, hd, mean);

    float4* pr = (float4*)(out + (size_t)b * 3 * OUTI_PIX) + idx4;
    float4* pg = pr + OUTI_PIX / 4;
    float4* pb = pr + 2 * (OUTI_PIX / 4);
    *pr = make_float4(r0, r1, r2, r3);
    *pg = make_float4(g0, g1, g2, g3);
    *pb = make_float4(b0, b1, b2, b3);
}

extern "C" void kernel_launch(void* const* d_in, const int* in_sizes, int n_in,
                              void* d_out, int out_size, void* d_ws, size_t ws_size,
                              hipStream_t stream) {
    const float* img = (const float*)d_in[0];
    const float* ms = (const float*)d_in[1];
    const float* bg = (const float*)d_in[2];
    const int* pads = (const int*)d_in[3];
    const int* csel = (const int*)d_in[4];
    const float* rcol = (const float*)d_in[5];
    const float* jit = (const float*)d_in[6];
    float* out = (float*)d_out;

    int* bbox = (int*)d_ws;                                        // 1 KB @ 0
    float* partials = (float*)((char*)d_ws + 1024);                // 16 KB @ 1 KB
    u64* bits = (u64*)((char*)d_ws + 1024 + 65536);                // 1.75 MB
    unsigned short* mid = (unsigned short*)((char*)d_ws + (2u << 20));  // 24 MB @ 2 MB
    float* outm = out + (size_t)B_SAMPLES * 3 * OUTI_PIX;

    hipMemsetAsync(bbox, 0x7F, B_SAMPLES * 4 * sizeof(int), stream);

    k_bbox<<<dim3(BBOX_CHUNKS, B_SAMPLES), 256, 0, stream>>>(ms, bbox, bits);
    k_resize_img<<<dim3(NGRP, B_SAMPLES), 256, 0, stream>>>(
        img, bg, pads, csel, rcol, jit, bbox, bits, mid, partials);
    k_resize_msk<<<dim3((OUTM * OUTM) / 256, B_SAMPLES), 256, 0, stream>>>(
        bits, pads, bbox, outm);
    k_jitter<<<dim3(OUTI_PIX / 4 / 256, B_SAMPLES), 256, 0, stream>>>(
        mid, out, jit, partials);
}

// Round 15
// 137.233 us; speedup vs baseline: 1.4581x; 1.4581x over previous
//
#include <hip/hip_runtime.h>

#define H_IN 448
#define W_IN 448
#define HW_IN (H_IN * W_IN)
#define BGW 488
#define BGHW (BGW * BGW)
#define OUTI 256
#define OUTI_PIX (OUTI * OUTI)
#define OUTM 64
#define B_SAMPLES 64
#define BBOX_CHUNKS 32
#define BBOX_ROWS (H_IN / BBOX_CHUNKS)  // 14
#define BITS_STRIDE 8                    // u64 words per row
#define WIN 256                          // staged column window (64 float4)

typedef unsigned long long u64;

__device__ __forceinline__ float clamp01(float x) { return fminf(fmaxf(x, 0.f), 1.f); }
__device__ __forceinline__ int clampi(int x, int lo, int hi) { return min(max(x, lo), hi); }

// ---------------- K1: bbox + packed mask bitmask (finer chunking) ----------------
__global__ void k_bbox(const float* __restrict__ ms, int* __restrict__ bbox,
                       u64* __restrict__ bits) {
    int b = blockIdx.y, chunk = blockIdx.x;
    int tid = threadIdx.x;
    int wave = tid >> 6, lane = tid & 63;
    const float* msB = ms + (size_t)b * HW_IN;
    u64* bitsB = bits + (size_t)b * H_IN * BITS_STRIDE;

    int miny = H_IN, maxy = -1, minx = W_IN, maxx = -1;
    for (int rr = wave; rr < BBOX_ROWS; rr += 4) {
        int row = chunk * BBOX_ROWS + rr;
        const float4* rowp = (const float4*)(msB + (size_t)row * W_IN);
#pragma unroll
        for (int sub = 0; sub < 2; ++sub) {
            int c4 = sub * 64 + lane;
            bool valid = c4 < (W_IN / 4);
            float4 v = rowp[min(c4, W_IN / 4 - 1)];
            bool a0 = valid && (v.x > 0.5f);
            bool a1 = valid && (v.y > 0.5f);
            bool a2 = valid && (v.z > 0.5f);
            bool a3 = valid && (v.w > 0.5f);
            u64 b0 = __ballot(a0), b1 = __ballot(a1), b2 = __ballot(a2), b3 = __ballot(a3);
            if (a0 | a1 | a2 | a3) {
                miny = min(miny, row); maxy = max(maxy, row);
                int xb = c4 * 4;
                if (a0) { minx = min(minx, xb);     maxx = max(maxx, xb); }
                if (a1) { minx = min(minx, xb + 1); maxx = max(maxx, xb + 1); }
                if (a2) { minx = min(minx, xb + 2); maxx = max(maxx, xb + 2); }
                if (a3) { minx = min(minx, xb + 3); maxx = max(maxx, xb + 3); }
            }
            if (lane < 4) {
                u64 w = (lane == 0) ? b0 : (lane == 1) ? b1 : (lane == 2) ? b2 : b3;
                bitsB[(size_t)row * BITS_STRIDE + sub * 4 + lane] = w;
            }
        }
    }
    __shared__ int s[4];
    if (tid == 0) { s[0] = H_IN; s[1] = -1; s[2] = W_IN; s[3] = -1; }
    __syncthreads();
    atomicMin(&s[0], miny); atomicMax(&s[1], maxy);
    atomicMin(&s[2], minx); atomicMax(&s[3], maxx);
    __syncthreads();
    if (tid == 0) {
        atomicMin(&bbox[b * 4 + 0], s[0]);
        atomicMin(&bbox[b * 4 + 1], -s[1]);
        atomicMin(&bbox[b * 4 + 2], s[2]);
        atomicMin(&bbox[b * 4 + 3], -s[3]);
    }
}

struct Geo {
    int miny, minx, h, w, top, left, Hp, Wp;
};
__device__ __forceinline__ Geo load_geo(const int* __restrict__ bbox,
                                        const int* __restrict__ pads, int b) {
    Geo g;
    g.miny = bbox[b * 4 + 0];
    int maxy = -bbox[b * 4 + 1];
    g.minx = bbox[b * 4 + 2];
    int maxx = -bbox[b * 4 + 3];
    int left = pads[b * 4 + 0], right = pads[b * 4 + 1];
    int top = pads[b * 4 + 2], bot = pads[b * 4 + 3];
    g.h = maxy - g.miny + 1;
    g.w = maxx - g.minx + 1;
    g.top = top; g.left = left;
    g.Hp = g.h + top + bot;
    g.Wp = g.w + left + right;
    return g;
}

__device__ __forceinline__ void src_coord(int i, int n_out, int size,
                                          int& t0, int& t1, float& frac) {
    float sizef = (float)size;
    float t = (i + 0.5f) * (sizef / (float)n_out) - 0.5f;
    t = fminf(fmaxf(t, 0.f), sizef - 1.f);
    t0 = (int)floorf(t);
    t1 = min(t0 + 1, size - 1);
    frac = t - (float)t0;
}

__device__ __forceinline__ bool mask_bit(const u64* rowbits, int c) {
    u64 w = rowbits[((c >> 8) << 2) | (c & 3)];
    return (w >> ((c >> 2) & 63)) & 1ULL;
}

__device__ __forceinline__ unsigned short q16(float x) {
    return (unsigned short)__float2uint_rn(x * 65535.f);
}

// ---------------- K2: half-row blocks (128 thr) with windowed staging ----------------
// Block = 128 output columns of one row. Stages 6 img planes + 6 bg planes of a
// 256-element aligned column window (12 KB LDS) -> ~13 blocks/CU, 13 independent
// 2-wave barrier domains. Math identical to round-13.
__global__ void __launch_bounds__(128) k_resize_img(
        const float* __restrict__ img, const float* __restrict__ bg,
        const int* __restrict__ pads, const int* __restrict__ csel,
        const float* __restrict__ rcol, const float* __restrict__ jit,
        const int* __restrict__ bbox, const u64* __restrict__ bits,
        unsigned short* __restrict__ mid, float* __restrict__ partials) {
    int bx = blockIdx.x;          // 0..511: oy = bx>>1, half = bx&1
    int oy = bx >> 1;
    int h = bx & 1;
    int b = blockIdx.y;
    int tid = threadIdx.x;        // 0..127
    int col = h * 128 + tid;

    Geo g = load_geo(bbox, pads, b);
    bool useBg = csel[b] > 2;
    float c0 = rcol[b * 3 + 0], c1 = rcol[b * 3 + 1], c2 = rcol[b * 3 + 2];
    float bfac = 0.9f + 0.2f * jit[b * 4 + 0];

    int y0, y1; float wy;
    src_coord(oy, OUTI, g.Hp, y0, y1, wy);
    int r0 = clampi(g.miny + y0 - g.top, 0, H_IN - 1);
    int r1 = clampi(g.miny + y1 - g.top, 0, H_IN - 1);
    bool incy0 = (y0 >= g.top) && (y0 < g.top + g.h);
    bool incy1 = (y1 >= g.top) && (y1 < g.top + g.h);

    // column window starts (aligned to float4). Per-half source span <= 246 elements.
    int xw0, xw1d; float wdum;
    src_coord(h * 128, OUTI, g.Wp, xw0, xw1d, wdum);
    int cW = clampi(g.minx + xw0 - g.left, 0, W_IN - 1);
    int cStart = min(cW & ~3, W_IN - WIN);     // 0..192
    int qStart = min(xw0 & ~3, BGW - WIN);     // 0..232

    __shared__ float s_im[6][WIN];   // 6 KB
    __shared__ float s_bg[6][WIN];   // 6 KB
    __shared__ u64 s_bits[2][BITS_STRIDE];
    __shared__ float ls[2];

    const float* imB = img + (size_t)b * 3 * HW_IN;
    const u64* bitsB = bits + (size_t)b * H_IN * BITS_STRIDE;

    // img: 6 planes x 64 float4 = 384 items over 128 threads (3 pow2 iters)
#pragma unroll
    for (int k = 0; k < 3; ++k) {
        int item = k * 128 + tid;     // 0..383
        int p = item >> 6;            // plane 0..5
        int idx = item & 63;
        int ky = p > 2;
        int ch = p - 3 * ky;
        int row = ky ? r1 : r0;
        ((float4*)s_im[p])[idx] =
            ((const float4*)(imB + (size_t)ch * HW_IN + (size_t)row * W_IN + cStart))[idx];
    }
    if (useBg) {
        const float* bgB = bg + (size_t)b * 3 * BGHW;
#pragma unroll
        for (int k = 0; k < 3; ++k) {
            int item = k * 128 + tid;
            int p = item >> 6;
            int idx = item & 63;
            int ky = p > 2;
            int ch = p - 3 * ky;
            int row = ky ? y1 : y0;   // <= Hp-1 <= 485 < 488
            ((float4*)s_bg[p])[idx] =
                ((const float4*)(bgB + (size_t)ch * BGHW + (size_t)row * BGW + qStart))[idx];
        }
    }
    if (tid < 16) {
        int ky = tid >> 3, idx = tid & 7;
        s_bits[ky][idx] = bitsB[(size_t)(ky ? r1 : r0) * BITS_STRIDE + idx];
    }
    __syncthreads();

    int x0, x1; float wx;
    src_coord(col, OUTI, g.Wp, x0, x1, wx);

    float acc0 = 0.f, acc1 = 0.f, acc2 = 0.f;
#pragma unroll
    for (int tap = 0; tap < 4; ++tap) {
        int ky = tap >> 1;
        int ky3 = ky * 3;
        int Q = (tap & 1) ? x1 : x0;
        float wgt = (ky ? wy : 1.f - wy) * ((tap & 1) ? wx : 1.f - wx);
        bool incy = ky ? incy1 : incy0;
        bool in_crop = incy && (Q >= g.left) && (Q < g.left + g.w);
        int c = clampi(g.minx + Q - g.left, 0, W_IN - 1);
        bool mm = in_crop && mask_bit(s_bits[ky], c);
        int cl = c - cStart;          // in [0, WIN)
        float i0 = s_im[ky3 + 0][cl], i1 = s_im[ky3 + 1][cl], i2 = s_im[ky3 + 2][cl];
        float b0, b1, b2;
        if (useBg) {   // block-uniform branch
            int ql = Q - qStart;      // in [0, WIN)
            b0 = s_bg[ky3 + 0][ql]; b1 = s_bg[ky3 + 1][ql]; b2 = s_bg[ky3 + 2][ql];
        } else {
            b0 = c0; b1 = c1; b2 = c2;
        }
        acc0 += wgt * (mm ? i0 : b0);
        acc1 += wgt * (mm ? i1 : b1);
        acc2 += wgt * (mm ? i2 : b2);
    }
    float o0 = clamp01(acc0 * bfac);
    float o1 = clamp01(acc1 * bfac);
    float o2 = clamp01(acc2 * bfac);
    size_t o = (size_t)b * 3 * OUTI_PIX + (size_t)oy * OUTI + col;
    mid[o] = q16(o0);
    mid[o + OUTI_PIX] = q16(o1);
    mid[o + 2 * OUTI_PIX] = q16(o2);

    // deterministic per-block gray partial (2 waves)
    float gsum = 0.299f * o0 + 0.587f * o1 + 0.114f * o2;
#pragma unroll
    for (int off = 32; off > 0; off >>= 1) gsum += __shfl_down(gsum, off, 64);
    int wave = tid >> 6, lane = tid & 63;
    if (lane == 0) ls[wave] = gsum;
    __syncthreads();
    if (tid == 0)
        partials[b * 512 + bx] = ls[0] + ls[1];
}

// ---------------- K2b: mask resize to 64x64 from the bitmask ----------------
__global__ void k_resize_msk(const u64* __restrict__ bits, const int* __restrict__ pads,
                             const int* __restrict__ bbox, float* __restrict__ outm) {
    int b = blockIdx.y;
    int pix = blockIdx.x * blockDim.x + threadIdx.x;
    int oy = pix >> 6, ox = pix & 63;

    Geo g = load_geo(bbox, pads, b);
    int y0, y1, x0, x1; float wy, wx;
    src_coord(oy, OUTM, g.Hp, y0, y1, wy);
    src_coord(ox, OUTM, g.Wp, x0, x1, wx);

    const u64* bitsB = bits + (size_t)b * H_IN * BITS_STRIDE;
    float acc = 0.f;
#pragma unroll
    for (int tap = 0; tap < 4; ++tap) {
        int P = (tap & 2) ? y1 : y0;
        int Q = (tap & 1) ? x1 : x0;
        float wgt = ((tap & 2) ? wy : 1.f - wy) * ((tap & 1) ? wx : 1.f - wx);
        bool in_crop = (P >= g.top) && (P < g.top + g.h) && (Q >= g.left) && (Q < g.left + g.w);
        int r = clampi(g.miny + P - g.top, 0, H_IN - 1);
        int c = clampi(g.minx + Q - g.left, 0, W_IN - 1);
        bool mm = in_crop && mask_bit(bitsB + (size_t)r * BITS_STRIDE, c);
        acc += wgt * (mm ? 1.f : 0.f);
    }
    outm[(size_t)b * (OUTM * OUTM) + pix] = acc;
}

// ---------------- K3: jitter, u16 intermediate -> f32 out ----------------
__device__ __forceinline__ void jitter_px(float& r, float& g, float& bl,
                                          float cc, float ssf, float hd, float mean) {
    r = clamp01(cc * r + (1.f - cc) * mean);
    g = clamp01(cc * g + (1.f - cc) * mean);
    bl = clamp01(cc * bl + (1.f - cc) * mean);
    float gray = 0.299f * r + 0.587f * g + 0.114f * bl;
    r = clamp01(ssf * r + (1.f - ssf) * gray);
    g = clamp01(ssf * g + (1.f - ssf) * gray);
    bl = clamp01(ssf * bl + (1.f - ssf) * gray);
    float mx = fmaxf(r, fmaxf(g, bl));
    float mn = fminf(r, fminf(g, bl));
    float d = mx - mn;
    float dsv = (d > 0.f) ? d : 1.f;
    float hch;
    if (mx == r) {
        float t = (g - bl) / dsv;
        t = fmodf(t, 6.f);
        if (t < 0.f) t += 6.f;
        hch = t;
    } else if (mx == g) {
        hch = (bl - r) / dsv + 2.f;
    } else {
        hch = (r - g) / dsv + 4.f;
    }
    hch = (d > 0.f) ? hch * (1.f / 6.f) : 0.f;
    float sat = (mx > 0.f) ? d / mx : 0.f;
    float v = mx;
    float hh = hch + hd;
    hh -= floorf(hh);
    float h6 = hh * 6.f;
    float fi = floorf(h6);
    float f = h6 - fi;
    float pp = v * (1.f - sat);
    float q = v * (1.f - f * sat);
    float t = v * (1.f - (1.f - f) * sat);
    int im = ((int)fi) % 6;
    float ro, go, bo;
    switch (im) {
        case 0: ro = v;  go = t;  bo = pp; break;
        case 1: ro = q;  go = v;  bo = pp; break;
        case 2: ro = pp; go = v;  bo = t;  break;
        case 3: ro = pp; go = q;  bo = v;  break;
        case 4: ro = t;  go = pp; bo = v;  break;
        default: ro = v; go = pp; bo = q;  break;
    }
    r = clamp01(ro); g = clamp01(go); bl = clamp01(bo);
}

__global__ void k_jitter(const unsigned short* __restrict__ mid,
                         float* __restrict__ out, const float* __restrict__ jit,
                         const float* __restrict__ partials) {
    int b = blockIdx.y;
    int tid = threadIdx.x;

    // 512 partials/sample: each thread folds 2, then standard reduce
    float pv = partials[b * 512 + tid] + partials[b * 512 + 256 + tid];
#pragma unroll
    for (int off = 32; off > 0; off >>= 1) pv += __shfl_down(pv, off, 64);
    __shared__ float ls[4];
    int wid = tid >> 6, lane = tid & 63;
    if (lane == 0) ls[wid] = pv;
    __syncthreads();
    float mean = (ls[0] + ls[1] + ls[2] + ls[3]) * (1.f / (float)OUTI_PIX);

    float cc = 0.9f + 0.2f * jit[b * 4 + 1];
    float ssf = 0.9f + 0.2f * jit[b * 4 + 2];
    float hd = -0.1f + 0.2f * jit[b * 4 + 3];

    int idx4 = blockIdx.x * blockDim.x + tid;
    const ushort4* mr = (const ushort4*)(mid + (size_t)b * 3 * OUTI_PIX) + idx4;
    const ushort4* mg = mr + OUTI_PIX / 4;
    const ushort4* mb = mr + 2 * (OUTI_PIX / 4);
    ushort4 ur = *mr, ug = *mg, ub = *mb;

    const float S = 1.f / 65535.f;
    float r0 = ur.x * S, r1 = ur.y * S, r2 = ur.z * S, r3 = ur.w * S;
    float g0 = ug.x * S, g1 = ug.y * S, g2 = ug.z * S, g3 = ug.w * S;
    float b0 = ub.x * S, b1 = ub.y * S, b2 = ub.z * S, b3 = ub.w * S;

    jitter_px(r0, g0, b0, cc, ssf, hd, mean);
    jitter_px(r1, g1, b1, cc, ssf, hd, mean);
    jitter_px(r2, g2, b2, cc, ssf, hd, mean);
    jitter_px(r3, g3, b3, cc, ssf, hd, mean);

    float4* pr = (float4*)(out + (size_t)b * 3 * OUTI_PIX) + idx4;
    float4* pg = pr + OUTI_PIX / 4;
    float4* pb = pr + 2 * (OUTI_PIX / 4);
    *pr = make_float4(r0, r1, r2, r3);
    *pg = make_float4(g0, g1, g2, g3);
    *pb = make_float4(b0, b1, b2, b3);
}

extern "C" void kernel_launch(void* const* d_in, const int* in_sizes, int n_in,
                              void* d_out, int out_size, void* d_ws, size_t ws_size,
                              hipStream_t stream) {
    const float* img = (const float*)d_in[0];
    const float* ms = (const float*)d_in[1];
    const float* bg = (const float*)d_in[2];
    const int* pads = (const int*)d_in[3];
    const int* csel = (const int*)d_in[4];
    const float* rcol = (const float*)d_in[5];
    const float* jit = (const float*)d_in[6];
    float* out = (float*)d_out;

    int* bbox = (int*)d_ws;                                            // 1 KB @ 0
    float* partials = (float*)((char*)d_ws + 1024);                    // 128 KB @ 1 KB
    u64* bits = (u64*)((char*)d_ws + 1024 + 512 * B_SAMPLES * 4);      // 1.75 MB
    unsigned short* mid = (unsigned short*)((char*)d_ws + (2u << 20)); // 24 MB @ 2 MB
    float* outm = out + (size_t)B_SAMPLES * 3 * OUTI_PIX;

    hipMemsetAsync(bbox, 0x7F, B_SAMPLES * 4 * sizeof(int), stream);

    k_bbox<<<dim3(BBOX_CHUNKS, B_SAMPLES), 256, 0, stream>>>(ms, bbox, bits);
    k_resize_img<<<dim3(OUTI * 2, B_SAMPLES), 128, 0, stream>>>(
        img, bg, pads, csel, rcol, jit, bbox, bits, mid, partials);
    k_resize_msk<<<dim3((OUTM * OUTM) / 256, B_SAMPLES), 256, 0, stream>>>(
        bits, pads, bbox, outm);
    k_jitter<<<dim3(OUTI_PIX / 4 / 256, B_SAMPLES), 256, 0, stream>>>(
        mid, out, jit, partials);
}

// Round 16
// 125.096 us; speedup vs baseline: 1.5995x; 1.0970x over previous
//
#include <hip/hip_runtime.h>

#define H_IN 448
#define W_IN 448
#define HW_IN (H_IN * W_IN)
#define BGW 488
#define BGHW (BGW * BGW)
#define OUTI 256
#define OUTI_PIX (OUTI * OUTI)
#define OUTM 64
#define B_SAMPLES 64
#define BBOX_CHUNKS 16
#define BBOX_ROWS (H_IN / BBOX_CHUNKS)  // 28
#define BITS_STRIDE 8                    // u64 words per row

typedef unsigned long long u64;

__device__ __forceinline__ float clamp01(float x) { return fminf(fmaxf(x, 0.f), 1.f); }
__device__ __forceinline__ int clampi(int x, int lo, int hi) { return min(max(x, lo), hi); }
__device__ __forceinline__ unsigned short q16(float x) {
    return (unsigned short)__float2uint_rn(x * 65535.f);
}

// ---------------- K1: bbox + packed mask bitmask (round-13 verbatim) ----------------
__global__ void k_bbox(const float* __restrict__ ms, int* __restrict__ bbox,
                       u64* __restrict__ bits) {
    int b = blockIdx.y, chunk = blockIdx.x;
    int tid = threadIdx.x;
    int wave = tid >> 6, lane = tid & 63;
    const float* msB = ms + (size_t)b * HW_IN;
    u64* bitsB = bits + (size_t)b * H_IN * BITS_STRIDE;

    int miny = H_IN, maxy = -1, minx = W_IN, maxx = -1;
    for (int rr = wave; rr < BBOX_ROWS; rr += 4) {
        int row = chunk * BBOX_ROWS + rr;
        const float4* rowp = (const float4*)(msB + (size_t)row * W_IN);
#pragma unroll
        for (int sub = 0; sub < 2; ++sub) {
            int c4 = sub * 64 + lane;
            bool valid = c4 < (W_IN / 4);
            float4 v = rowp[min(c4, W_IN / 4 - 1)];
            bool a0 = valid && (v.x > 0.5f);
            bool a1 = valid && (v.y > 0.5f);
            bool a2 = valid && (v.z > 0.5f);
            bool a3 = valid && (v.w > 0.5f);
            u64 b0 = __ballot(a0), b1 = __ballot(a1), b2 = __ballot(a2), b3 = __ballot(a3);
            if (a0 | a1 | a2 | a3) {
                miny = min(miny, row); maxy = max(maxy, row);
                int xb = c4 * 4;
                if (a0) { minx = min(minx, xb);     maxx = max(maxx, xb); }
                if (a1) { minx = min(minx, xb + 1); maxx = max(maxx, xb + 1); }
                if (a2) { minx = min(minx, xb + 2); maxx = max(maxx, xb + 2); }
                if (a3) { minx = min(minx, xb + 3); maxx = max(maxx, xb + 3); }
            }
            if (lane < 4) {
                u64 w = (lane == 0) ? b0 : (lane == 1) ? b1 : (lane == 2) ? b2 : b3;
                bitsB[(size_t)row * BITS_STRIDE + sub * 4 + lane] = w;
            }
        }
    }
    __shared__ int s[4];
    if (tid == 0) { s[0] = H_IN; s[1] = -1; s[2] = W_IN; s[3] = -1; }
    __syncthreads();
    atomicMin(&s[0], miny); atomicMax(&s[1], maxy);
    atomicMin(&s[2], minx); atomicMax(&s[3], maxx);
    __syncthreads();
    if (tid == 0) {
        atomicMin(&bbox[b * 4 + 0], s[0]);
        atomicMin(&bbox[b * 4 + 1], -s[1]);
        atomicMin(&bbox[b * 4 + 2], s[2]);
        atomicMin(&bbox[b * 4 + 3], -s[3]);
    }
}

struct Geo {
    int miny, minx, h, w, top, left, Hp, Wp;
};
__device__ __forceinline__ Geo load_geo(const int* __restrict__ bbox,
                                        const int* __restrict__ pads, int b) {
    Geo g;
    g.miny = bbox[b * 4 + 0];
    int maxy = -bbox[b * 4 + 1];
    g.minx = bbox[b * 4 + 2];
    int maxx = -bbox[b * 4 + 3];
    int left = pads[b * 4 + 0], right = pads[b * 4 + 1];
    int top = pads[b * 4 + 2], bot = pads[b * 4 + 3];
    g.h = maxy - g.miny + 1;
    g.w = maxx - g.minx + 1;
    g.top = top; g.left = left;
    g.Hp = g.h + top + bot;
    g.Wp = g.w + left + right;
    return g;
}

__device__ __forceinline__ void src_coord(int i, int n_out, int size,
                                          int& t0, int& t1, float& frac) {
    float sizef = (float)size;
    float t = (i + 0.5f) * (sizef / (float)n_out) - 0.5f;
    t = fminf(fmaxf(t, 0.f), sizef - 1.f);
    t0 = (int)floorf(t);
    t1 = min(t0 + 1, size - 1);
    frac = t - (float)t0;
}

__device__ __forceinline__ bool mask_bit(const u64* rowbits, int c) {
    u64 w = rowbits[((c >> 8) << 2) | (c & 3)];
    return (w >> ((c >> 2) & 63)) & 1ULL;
}

struct RowGeom {
    int y0, y1, r0, r1;
    float wy;
    bool incy0, incy1;
};
__device__ __forceinline__ RowGeom row_geom(const Geo& g, int oy) {
    RowGeom rg;
    src_coord(oy, OUTI, g.Hp, rg.y0, rg.y1, rg.wy);
    rg.r0 = clampi(g.miny + rg.y0 - g.top, 0, H_IN - 1);
    rg.r1 = clampi(g.miny + rg.y1 - g.top, 0, H_IN - 1);
    rg.incy0 = (rg.y0 >= g.top) && (rg.y0 < g.top + g.h);
    rg.incy1 = (rg.y1 >= g.top) && (rg.y1 < g.top + g.h);
    return rg;
}

// ---------------- K2: 2-row 512-thread blocks, u16 LDS staging (32 waves/CU) ----------------
__global__ void __launch_bounds__(512, 8) k_resize_img(
        const float* __restrict__ img, const float* __restrict__ bg,
        const int* __restrict__ pads, const int* __restrict__ csel,
        const float* __restrict__ rcol, const float* __restrict__ jit,
        const int* __restrict__ bbox, const u64* __restrict__ bits,
        unsigned short* __restrict__ mid, float* __restrict__ partials) {
    int pair = blockIdx.x;        // 0..127 -> rows 2*pair, 2*pair+1
    int b = blockIdx.y;
    int tid = threadIdx.x;        // 0..511
    int trow = tid >> 8;          // 0/1
    int col = tid & 255;

    Geo g = load_geo(bbox, pads, b);
    bool useBg = csel[b] > 2;
    float c0 = rcol[b * 3 + 0], c1 = rcol[b * 3 + 1], c2 = rcol[b * 3 + 2];
    float bfac = 0.9f + 0.2f * jit[b * 4 + 0];

    RowGeom rg0 = row_geom(g, pair * 2 + 0);
    RowGeom rg1 = row_geom(g, pair * 2 + 1);

    // 12 img planes / 12 bg planes: slot s = 0..3 = {rg0.r0, rg0.r1, rg1.r0, rg1.r1}
    __shared__ unsigned short s_im[12][W_IN];   // 10.8 KB
    __shared__ unsigned short s_bg[12][BGW];    // 11.7 KB
    __shared__ u64 s_bits[4][BITS_STRIDE];      // 256 B
    __shared__ float ls[8];

    const float* imB = img + (size_t)b * 3 * HW_IN;
    const u64* bitsB = bits + (size_t)b * H_IN * BITS_STRIDE;

    // img staging: 12 planes x 112 float4 in 128-slots = 1536 items over 512 thr (3 iters)
#pragma unroll
    for (int k = 0; k < 3; ++k) {
        int item = k * 512 + tid;     // 0..1535
        int p = item >> 7;            // plane 0..11
        int idx = item & 127;
        if (idx < W_IN / 4) {
            int s = p / 3, ch = p - 3 * (p / 3);
            int row = (s == 0) ? rg0.r0 : (s == 1) ? rg0.r1 : (s == 2) ? rg1.r0 : rg1.r1;
            float4 v = ((const float4*)(imB + (size_t)ch * HW_IN + (size_t)row * W_IN))[idx];
            ushort4 u = {q16(v.x), q16(v.y), q16(v.z), q16(v.w)};
            *(ushort4*)&s_im[p][idx * 4] = u;
        }
    }
    if (useBg) {
        const float* bgB = bg + (size_t)b * 3 * BGHW;
#pragma unroll
        for (int k = 0; k < 3; ++k) {
            int item = k * 512 + tid;
            int p = item >> 7;
            int idx = item & 127;
            if (idx < BGW / 4) {
                int s = p / 3, ch = p - 3 * (p / 3);
                int row = (s == 0) ? rg0.y0 : (s == 1) ? rg0.y1 : (s == 2) ? rg1.y0 : rg1.y1;
                float4 v = ((const float4*)(bgB + (size_t)ch * BGHW + (size_t)row * BGW))[idx];
                ushort4 u = {q16(v.x), q16(v.y), q16(v.z), q16(v.w)};
                *(ushort4*)&s_bg[p][idx * 4] = u;
            }
        }
    }
    if (tid < 32) {
        int s = tid >> 3, idx = tid & 7;
        int row = (s == 0) ? rg0.r0 : (s == 1) ? rg0.r1 : (s == 2) ? rg1.r0 : rg1.r1;
        s_bits[s][idx] = bitsB[(size_t)row * BITS_STRIDE + idx];
    }
    __syncthreads();

    // per-thread: one output pixel (row trow of the pair, column col)
    RowGeom rgt;
    rgt.wy = trow ? rg1.wy : rg0.wy;
    rgt.incy0 = trow ? rg1.incy0 : rg0.incy0;
    rgt.incy1 = trow ? rg1.incy1 : rg0.incy1;

    int x0, x1; float wx;
    src_coord(col, OUTI, g.Wp, x0, x1, wx);

    const float S = 1.f / 65535.f;
    float acc0 = 0.f, acc1 = 0.f, acc2 = 0.f;
#pragma unroll
    for (int tap = 0; tap < 4; ++tap) {
        int ky = tap >> 1;
        int slot = trow * 2 + ky;      // src-row slot 0..3
        int p3 = slot * 3;
        int Q = (tap & 1) ? x1 : x0;
        float wgt = (ky ? rgt.wy : 1.f - rgt.wy) * ((tap & 1) ? wx : 1.f - wx);
        bool incy = ky ? rgt.incy1 : rgt.incy0;
        bool in_crop = incy && (Q >= g.left) && (Q < g.left + g.w);
        int c = clampi(g.minx + Q - g.left, 0, W_IN - 1);
        bool mm = in_crop && mask_bit(s_bits[slot], c);
        float i0 = s_im[p3 + 0][c] * S;
        float i1 = s_im[p3 + 1][c] * S;
        float i2 = s_im[p3 + 2][c] * S;
        float b0, b1, b2;
        if (useBg) {   // block-uniform branch
            b0 = s_bg[p3 + 0][Q] * S;
            b1 = s_bg[p3 + 1][Q] * S;
            b2 = s_bg[p3 + 2][Q] * S;
        } else {
            b0 = c0; b1 = c1; b2 = c2;
        }
        acc0 += wgt * (mm ? i0 : b0);
        acc1 += wgt * (mm ? i1 : b1);
        acc2 += wgt * (mm ? i2 : b2);
    }
    float o0 = clamp01(acc0 * bfac);
    float o1 = clamp01(acc1 * bfac);
    float o2 = clamp01(acc2 * bfac);
    int oy = pair * 2 + trow;
    size_t o = (size_t)b * 3 * OUTI_PIX + (size_t)oy * OUTI + col;
    mid[o] = q16(o0);
    mid[o + OUTI_PIX] = q16(o1);
    mid[o + 2 * OUTI_PIX] = q16(o2);

    // deterministic per-block gray partial (8 waves)
    float gsum = 0.299f * o0 + 0.587f * o1 + 0.114f * o2;
#pragma unroll
    for (int off = 32; off > 0; off >>= 1) gsum += __shfl_down(gsum, off, 64);
    int wave = tid >> 6, lane = tid & 63;
    if (lane == 0) ls[wave] = gsum;
    __syncthreads();
    if (tid == 0) {
        float t = 0.f;
#pragma unroll
        for (int k = 0; k < 8; ++k) t += ls[k];
        partials[b * 128 + pair] = t;
    }
}

// ---------------- K2b: mask resize to 64x64 from the bitmask (round-13 verbatim) --------
__global__ void k_resize_msk(const u64* __restrict__ bits, const int* __restrict__ pads,
                             const int* __restrict__ bbox, float* __restrict__ outm) {
    int b = blockIdx.y;
    int pix = blockIdx.x * blockDim.x + threadIdx.x;
    int oy = pix >> 6, ox = pix & 63;

    Geo g = load_geo(bbox, pads, b);
    int y0, y1, x0, x1; float wy, wx;
    src_coord(oy, OUTM, g.Hp, y0, y1, wy);
    src_coord(ox, OUTM, g.Wp, x0, x1, wx);

    const u64* bitsB = bits + (size_t)b * H_IN * BITS_STRIDE;
    float acc = 0.f;
#pragma unroll
    for (int tap = 0; tap < 4; ++tap) {
        int P = (tap & 2) ? y1 : y0;
        int Q = (tap & 1) ? x1 : x0;
        float wgt = ((tap & 2) ? wy : 1.f - wy) * ((tap & 1) ? wx : 1.f - wx);
        bool in_crop = (P >= g.top) && (P < g.top + g.h) && (Q >= g.left) && (Q < g.left + g.w);
        int r = clampi(g.miny + P - g.top, 0, H_IN - 1);
        int c = clampi(g.minx + Q - g.left, 0, W_IN - 1);
        bool mm = in_crop && mask_bit(bitsB + (size_t)r * BITS_STRIDE, c);
        acc += wgt * (mm ? 1.f : 0.f);
    }
    outm[(size_t)b * (OUTM * OUTM) + pix] = acc;
}

// ---------------- K3: jitter, u16 intermediate -> f32 out (128 partials) ----------------
__device__ __forceinline__ void jitter_px(float& r, float& g, float& bl,
                                          float cc, float ssf, float hd, float mean) {
    r = clamp01(cc * r + (1.f - cc) * mean);
    g = clamp01(cc * g + (1.f - cc) * mean);
    bl = clamp01(cc * bl + (1.f - cc) * mean);
    float gray = 0.299f * r + 0.587f * g + 0.114f * bl;
    r = clamp01(ssf * r + (1.f - ssf) * gray);
    g = clamp01(ssf * g + (1.f - ssf) * gray);
    bl = clamp01(ssf * bl + (1.f - ssf) * gray);
    float mx = fmaxf(r, fmaxf(g, bl));
    float mn = fminf(r, fminf(g, bl));
    float d = mx - mn;
    float dsv = (d > 0.f) ? d : 1.f;
    float hch;
    if (mx == r) {
        float t = (g - bl) / dsv;
        t = fmodf(t, 6.f);
        if (t < 0.f) t += 6.f;
        hch = t;
    } else if (mx == g) {
        hch = (bl - r) / dsv + 2.f;
    } else {
        hch = (r - g) / dsv + 4.f;
    }
    hch = (d > 0.f) ? hch * (1.f / 6.f) : 0.f;
    float sat = (mx > 0.f) ? d / mx : 0.f;
    float v = mx;
    float hh = hch + hd;
    hh -= floorf(hh);
    float h6 = hh * 6.f;
    float fi = floorf(h6);
    float f = h6 - fi;
    float pp = v * (1.f - sat);
    float q = v * (1.f - f * sat);
    float t = v * (1.f - (1.f - f) * sat);
    int im = ((int)fi) % 6;
    float ro, go, bo;
    switch (im) {
        case 0: ro = v;  go = t;  bo = pp; break;
        case 1: ro = q;  go = v;  bo = pp; break;
        case 2: ro = pp; go = v;  bo = t;  break;
        case 3: ro = pp; go = q;  bo = v;  break;
        case 4: ro = t;  go = pp; bo = v;  break;
        default: ro = v; go = pp; bo = q;  break;
    }
    r = clamp01(ro); g = clamp01(go); bl = clamp01(bo);
}

__global__ void k_jitter(const unsigned short* __restrict__ mid,
                         float* __restrict__ out, const float* __restrict__ jit,
                         const float* __restrict__ partials) {
    int b = blockIdx.y;
    int tid = threadIdx.x;

    float pv = (tid < 128) ? partials[b * 128 + tid] : 0.f;
#pragma unroll
    for (int off = 32; off > 0; off >>= 1) pv += __shfl_down(pv, off, 64);
    __shared__ float ls[4];
    int wid = tid >> 6, lane = tid & 63;
    if (lane == 0) ls[wid] = pv;
    __syncthreads();
    float mean = (ls[0] + ls[1] + ls[2] + ls[3]) * (1.f / (float)OUTI_PIX);

    float cc = 0.9f + 0.2f * jit[b * 4 + 1];
    float ssf = 0.9f + 0.2f * jit[b * 4 + 2];
    float hd = -0.1f + 0.2f * jit[b * 4 + 3];

    int idx4 = blockIdx.x * blockDim.x + tid;
    const ushort4* mr = (const ushort4*)(mid + (size_t)b * 3 * OUTI_PIX) + idx4;
    const ushort4* mg = mr + OUTI_PIX / 4;
    const ushort4* mb = mr + 2 * (OUTI_PIX / 4);
    ushort4 ur = *mr, ug = *mg, ub = *mb;

    const float S = 1.f / 65535.f;
    float r0 = ur.x * S, r1 = ur.y * S, r2 = ur.z * S, r3 = ur.w * S;
    float g0 = ug.x * S, g1 = ug.y * S, g2 = ug.z * S, g3 = ug.w * S;
    float b0 = ub.x * S, b1 = ub.y * S, b2 = ub.z * S, b3 = ub.w * S;

    jitter_px(r0, g0, b0, cc, ssf, hd, mean);
    jitter_px(r1, g1, b1, cc, ssf, hd, mean);
    jitter_px(r2, g2, b2, cc, ssf, hd, mean);
    jitter_px(r3, g3, b3, cc, ssf, hd, mean);

    float4* pr = (float4*)(out + (size_t)b * 3 * OUTI_PIX) + idx4;
    float4* pg = pr + OUTI_PIX / 4;
    float4* pb = pr + 2 * (OUTI_PIX / 4);
    *pr = make_float4(r0, r1, r2, r3);
    *pg = make_float4(g0, g1, g2, g3);
    *pb = make_float4(b0, b1, b2, b3);
}

extern "C" void kernel_launch(void* const* d_in, const int* in_sizes, int n_in,
                              void* d_out, int out_size, void* d_ws, size_t ws_size,
                              hipStream_t stream) {
    const float* img = (const float*)d_in[0];
    const float* ms = (const float*)d_in[1];
    const float* bg = (const float*)d_in[2];
    const int* pads = (const int*)d_in[3];
    const int* csel = (const int*)d_in[4];
    const float* rcol = (const float*)d_in[5];
    const float* jit = (const float*)d_in[6];
    float* out = (float*)d_out;

    int* bbox = (int*)d_ws;                                            // 1 KB @ 0
    float* partials = (float*)((char*)d_ws + 1024);                    // 32 KB @ 1 KB
    u64* bits = (u64*)((char*)d_ws + 1024 + 65536);                    // 1.75 MB
    unsigned short* mid = (unsigned short*)((char*)d_ws + (2u << 20)); // 24 MB @ 2 MB
    float* outm = out + (size_t)B_SAMPLES * 3 * OUTI_PIX;

    hipMemsetAsync(bbox, 0x7F, B_SAMPLES * 4 * sizeof(int), stream);

    k_bbox<<<dim3(BBOX_CHUNKS, B_SAMPLES), 256, 0, stream>>>(ms, bbox, bits);
    k_resize_img<<<dim3(OUTI / 2, B_SAMPLES), 512, 0, stream>>>(
        img, bg, pads, csel, rcol, jit, bbox, bits, mid, partials);
    k_resize_msk<<<dim3((OUTM * OUTM) / 256, B_SAMPLES), 256, 0, stream>>>(
        bits, pads, bbox, outm);
    k_jitter<<<dim3(OUTI_PIX / 4 / 256, B_SAMPLES), 256, 0, stream>>>(
        mid, out, jit, partials);
}